// Round 1
// baseline (1320.536 us; speedup 1.0000x reference)
//
#include <hip/hip_runtime.h>
#include <hip/hip_bf16.h>
#include <math.h>

#define DIM 1024
#define NUM_ACTIONS 8
#define ACTION_BINS 256
#define D_STATE 16
#define D_CONV 4
#define D_INNER 2048
#define DT_RANK 64
#define BATCH 512
#define SEQ 64
#define NTOK (BATCH * NUM_ACTIONS)   // 4096 tokens

// ---------------------------------------------------------------------------
// Kernel 1: sos = mean over sequence of encoded_state -> tokens[:, 0, :]
// grid (DIM/256, BATCH), block 256. Coalesced: lanes over d, loop over s.
// ---------------------------------------------------------------------------
__global__ __launch_bounds__(256)
void sos_mean_kernel(const float* __restrict__ enc, float* __restrict__ tokens) {
    int b = blockIdx.y;
    int d = blockIdx.x * 256 + threadIdx.x;
    const float* p = enc + (size_t)b * SEQ * DIM + d;
    float acc = 0.f;
#pragma unroll 8
    for (int s = 0; s < SEQ; ++s) acc += p[(size_t)s * DIM];
    tokens[(size_t)b * NUM_ACTIONS * DIM + d] = acc * (1.0f / SEQ);
}

// ---------------------------------------------------------------------------
// Kernel 2: gather action-bin embeddings -> tokens[:, 1+i, :]
// grid (BATCH, NUM_ACTIONS-1), block 256 (float4 copy of 1024 floats)
// ---------------------------------------------------------------------------
__global__ __launch_bounds__(256)
void gather_tokens_kernel(const int* __restrict__ actions,
                          const float* __restrict__ abe,
                          float* __restrict__ tokens) {
    int b = blockIdx.x;
    int i = blockIdx.y;  // 0..6
    int a = actions[b * (NUM_ACTIONS - 1) + i];
    const float4* src = (const float4*)(abe + ((size_t)i * ACTION_BINS + a) * DIM);
    float4* dst = (float4*)(tokens + ((size_t)b * NUM_ACTIONS + 1 + i) * DIM);
    dst[threadIdx.x] = src[threadIdx.x];
}

// ---------------------------------------------------------------------------
// Generic tiled fp32 GEMM: out[M,N] = act(A[M,K] * W[N,K]^T + bias)
// A row stride lda, W row stride ldw, out row stride ldo. Batched via
// blockIdx.z with element strides. wroll=1 remaps W row r -> (r+1)%N.
// act: 0 none, 1 softplus, 2 sigmoid.
// Requires K % 16 == 0 and 16B-aligned rows (lda/ldw/k multiples of 4).
// Block 256 threads; each thread computes (TM/16)x(TN/16) outputs arranged
// as (TM/64)x(TN/64) sub-blocks of 4x4 (float4-friendly, <=2-way LDS conflicts).
// ---------------------------------------------------------------------------
template <int TM, int TN>
__global__ __launch_bounds__(256)
void gemm_bt(const float* __restrict__ A, int lda, long long aStride,
             const float* __restrict__ W, int ldw, long long wStride, int wroll,
             const float* __restrict__ bias,
             float* __restrict__ out, int ldo, long long oStride,
             int M, int N, int K, int act) {
    constexpr int TK = 16;
    constexpr int GM = TM / 64;
    constexpr int GN = TN / 64;
    __shared__ float As[TK][TM + 4];
    __shared__ float Ws[TK][TN + 4];

    A += (size_t)blockIdx.z * aStride;
    W += (size_t)blockIdx.z * wStride;
    out += (size_t)blockIdx.z * oStride;

    int tid = threadIdx.x;
    int tx = tid & 15, ty = tid >> 4;
    int m0 = blockIdx.x * TM, n0 = blockIdx.y * TN;

    float acc[GM * 4][GN * 4];
#pragma unroll
    for (int i = 0; i < GM * 4; ++i)
#pragma unroll
        for (int j = 0; j < GN * 4; ++j) acc[i][j] = 0.f;

    for (int k0 = 0; k0 < K; k0 += TK) {
        // Stage A tile (TM x TK) into LDS as As[k][m]
#pragma unroll
        for (int l = 0; l < TM / 64; ++l) {
            int idx = tid + l * 256;
            int r = idx >> 2;
            int kk = (idx & 3) << 2;
            float4 v = make_float4(0.f, 0.f, 0.f, 0.f);
            int gr = m0 + r;
            if (gr < M) v = *(const float4*)(A + (size_t)gr * lda + k0 + kk);
            As[kk + 0][r] = v.x; As[kk + 1][r] = v.y;
            As[kk + 2][r] = v.z; As[kk + 3][r] = v.w;
        }
        // Stage W tile (TN x TK) into LDS as Ws[k][n]
#pragma unroll
        for (int l = 0; l < TN / 64; ++l) {
            int idx = tid + l * 256;
            int r = idx >> 2;
            int kk = (idx & 3) << 2;
            int wr = n0 + r;
            if (wroll) wr = (wr + 1) % N;
            float4 v = make_float4(0.f, 0.f, 0.f, 0.f);
            if (wr < N) v = *(const float4*)(W + (size_t)wr * ldw + k0 + kk);
            Ws[kk + 0][r] = v.x; Ws[kk + 1][r] = v.y;
            Ws[kk + 2][r] = v.z; Ws[kk + 3][r] = v.w;
        }
        __syncthreads();

#pragma unroll
        for (int k = 0; k < TK; ++k) {
            float a[GM * 4], bb[GN * 4];
#pragma unroll
            for (int g = 0; g < GM; ++g) {
                float4 v = *(const float4*)&As[k][g * 64 + ty * 4];
                a[g * 4 + 0] = v.x; a[g * 4 + 1] = v.y;
                a[g * 4 + 2] = v.z; a[g * 4 + 3] = v.w;
            }
#pragma unroll
            for (int g = 0; g < GN; ++g) {
                float4 v = *(const float4*)&Ws[k][g * 64 + tx * 4];
                bb[g * 4 + 0] = v.x; bb[g * 4 + 1] = v.y;
                bb[g * 4 + 2] = v.z; bb[g * 4 + 3] = v.w;
            }
#pragma unroll
            for (int i = 0; i < GM * 4; ++i)
#pragma unroll
                for (int j = 0; j < GN * 4; ++j)
                    acc[i][j] += a[i] * bb[j];
        }
        __syncthreads();
    }

    // Epilogue
#pragma unroll
    for (int i = 0; i < GM * 4; ++i) {
        int m = m0 + (i >> 2) * 64 + ty * 4 + (i & 3);
        if (m >= M) continue;
#pragma unroll
        for (int j = 0; j < GN * 4; ++j) {
            int n = n0 + (j >> 2) * 64 + tx * 4 + (j & 3);
            if (n >= N) continue;
            float v = acc[i][j];
            if (bias) v += bias[n];
            if (act == 1) v = (v > 20.0f) ? v : log1pf(__expf(v));   // softplus
            else if (act == 2) v = 1.0f / (1.0f + __expf(-v));        // sigmoid
            out[(size_t)m * ldo + n] = v;
        }
    }
}

// ---------------------------------------------------------------------------
// Kernel: causal depthwise conv1d (kernel 4) + bias + SiLU.
// xh = xz[:, :, :D_INNER] (row stride 2*D_INNER). Writes xc [NTOK, D_INNER].
// grid (D_INNER/256, BATCH)
// ---------------------------------------------------------------------------
__global__ __launch_bounds__(256)
void conv_silu_kernel(const float* __restrict__ xz, const float* __restrict__ conv_w,
                      const float* __restrict__ conv_b, float* __restrict__ xc) {
    int c = blockIdx.x * 256 + threadIdx.x;
    int b = blockIdx.y;
    float4 w = *(const float4*)(conv_w + (size_t)c * 4);
    float bias = conv_b[c];
    const float* px = xz + (size_t)b * NUM_ACTIONS * (2 * D_INNER) + c;
    float x[NUM_ACTIONS];
#pragma unroll
    for (int t = 0; t < NUM_ACTIONS; ++t) x[t] = px[(size_t)t * (2 * D_INNER)];
    float* po = xc + (size_t)b * NUM_ACTIONS * D_INNER + c;
#pragma unroll
    for (int t = 0; t < NUM_ACTIONS; ++t) {
        float s = bias + x[t] * w.w;               // conv_w[c,3] hits current t
        if (t >= 1) s += x[t - 1] * w.z;
        if (t >= 2) s += x[t - 2] * w.y;
        if (t >= 3) s += x[t - 3] * w.x;
        po[(size_t)t * D_INNER] = s * (1.0f / (1.0f + __expf(-s)));  // SiLU
    }
}

// ---------------------------------------------------------------------------
// Kernel: selective scan over l=8, fused with y*silu(z).
// u = xc, delta precomputed, B/C from x_dbl cols [64:80)/[80:96), z from
// xz[:, D_INNER:], output y*silu(z) written into xz[:, :D_INNER].
// grid (D_INNER/256, BATCH)
// ---------------------------------------------------------------------------
__global__ __launch_bounds__(256)
void scan_kernel(const float* __restrict__ u_, const float* __restrict__ delta_,
                 const float* __restrict__ x_dbl, const float* __restrict__ A_log,
                 const float* __restrict__ Dp, float* __restrict__ xz) {
    int b = blockIdx.y;
    int d = blockIdx.x * 256 + threadIdx.x;
    __shared__ float Bs[NUM_ACTIONS][D_STATE], Cs[NUM_ACTIONS][D_STATE];
    int tid = threadIdx.x;
    if (tid < 128) {
        int t = tid >> 4, n = tid & 15;
        Bs[t][n] = x_dbl[(size_t)(b * NUM_ACTIONS + t) * 96 + 64 + n];
    } else {
        int q = tid - 128;
        int t = q >> 4, n = q & 15;
        Cs[t][n] = x_dbl[(size_t)(b * NUM_ACTIONS + t) * 96 + 80 + n];
    }
    __syncthreads();

    float Av[D_STATE];
#pragma unroll
    for (int n = 0; n < D_STATE; ++n) Av[n] = -__expf(A_log[(size_t)d * D_STATE + n]);
    float Dv = Dp[d];
    float h[D_STATE];
#pragma unroll
    for (int n = 0; n < D_STATE; ++n) h[n] = 0.f;

#pragma unroll
    for (int t = 0; t < NUM_ACTIONS; ++t) {
        size_t tok = (size_t)(b * NUM_ACTIONS + t);
        float dt = delta_[tok * D_INNER + d];
        float uu = u_[tok * D_INNER + d];
        float zz = xz[tok * (2 * D_INNER) + D_INNER + d];
        float du = dt * uu;
        float y = uu * Dv;
#pragma unroll
        for (int n = 0; n < D_STATE; ++n) {
            h[n] = __expf(dt * Av[n]) * h[n] + du * Bs[t][n];
            y += h[n] * Cs[t][n];
        }
        float sz = zz * (1.0f / (1.0f + __expf(-zz)));  // silu(z)
        xz[tok * (2 * D_INNER) + d] = y * sz;           // overwrite xh half with ys
    }
}

// ---------------------------------------------------------------------------
extern "C" void kernel_launch(void* const* d_in, const int* in_sizes, int n_in,
                              void* d_out, int out_size, void* d_ws, size_t ws_size,
                              hipStream_t stream) {
    const float* enc        = (const float*)d_in[0];
    const int*   actions    = (const int*)d_in[1];
    const float* abe        = (const float*)d_in[2];
    // d_in[3] = gamma (unused by reference)
    const float* in_proj_w  = (const float*)d_in[4];
    const float* conv_w     = (const float*)d_in[5];
    const float* conv_b     = (const float*)d_in[6];
    const float* x_proj_w   = (const float*)d_in[7];
    const float* dt_proj_w  = (const float*)d_in[8];
    const float* dt_proj_b  = (const float*)d_in[9];
    const float* A_log      = (const float*)d_in[10];
    const float* D_param    = (const float*)d_in[11];
    const float* out_proj_w = (const float*)d_in[12];
    float* out = (float*)d_out;

    float* ws = (float*)d_ws;
    float* tokens = ws;                                   // [4096,1024] (reused as embed)
    float* xz     = tokens + (size_t)NTOK * DIM;          // [4096,4096] xh||z; ys overwrites xh
    float* xc     = xz + (size_t)NTOK * 2 * D_INNER;      // [4096,2048] u
    float* x_dbl  = xc + (size_t)NTOK * D_INNER;          // [4096,96]   dt||B||C
    float* delta  = x_dbl + (size_t)NTOK * 96;            // [4096,2048]
    // total 38.1M floats ~= 153 MB of d_ws

    // 1) tokens
    sos_mean_kernel<<<dim3(DIM / 256, BATCH), 256, 0, stream>>>(enc, tokens);
    gather_tokens_kernel<<<dim3(BATCH, NUM_ACTIONS - 1), 256, 0, stream>>>(actions, abe, tokens);

    // 2) in_proj: xz[4096,4096] = tokens @ in_proj_w^T
    gemm_bt<128, 128><<<dim3(NTOK / 128, (2 * D_INNER) / 128), 256, 0, stream>>>(
        tokens, DIM, 0, in_proj_w, DIM, 0, 0, nullptr,
        xz, 2 * D_INNER, 0, NTOK, 2 * D_INNER, DIM, 0);

    // 3) conv + silu -> xc (u)
    conv_silu_kernel<<<dim3(D_INNER / 256, BATCH), 256, 0, stream>>>(xz, conv_w, conv_b, xc);

    // 4) x_proj: x_dbl[4096,96] = xc @ x_proj_w^T
    gemm_bt<64, 64><<<dim3(NTOK / 64, 2), 256, 0, stream>>>(
        xc, D_INNER, 0, x_proj_w, D_INNER, 0, 0, nullptr,
        x_dbl, 96, 0, NTOK, 96, D_INNER, 0);

    // 5) delta = softplus(x_dbl[:, :64] @ dt_proj_w^T + dt_proj_b)
    gemm_bt<64, 64><<<dim3(NTOK / 64, D_INNER / 64), 256, 0, stream>>>(
        x_dbl, 96, 0, dt_proj_w, DT_RANK, 0, 0, dt_proj_b,
        delta, D_INNER, 0, NTOK, D_INNER, DT_RANK, 1);

    // 6) selective scan + y*silu(z) -> xz[:, :D_INNER]
    scan_kernel<<<dim3(D_INNER / 256, BATCH), 256, 0, stream>>>(
        xc, delta, x_dbl, A_log, D_param, xz);

    // 7) out_proj: embed[4096,1024] = ys @ out_proj_w^T (ys has row stride 4096)
    gemm_bt<128, 128><<<dim3(NTOK / 128, DIM / 128), 256, 0, stream>>>(
        xz, 2 * D_INNER, 0, out_proj_w, D_INNER, 0, 0, nullptr,
        tokens, DIM, 0, NTOK, DIM, D_INNER, 0);

    // 8) logits: out[b,n,a] = sigmoid(embed[b,n,:] . abe[n,(a+1)%256,:])
    //    batched over n = blockIdx.z (8 slots)
    gemm_bt<64, 64><<<dim3(BATCH / 64, ACTION_BINS / 64, NUM_ACTIONS), 256, 0, stream>>>(
        tokens, NUM_ACTIONS * DIM, DIM,
        abe, DIM, (long long)ACTION_BINS * DIM, /*wroll=*/1, nullptr,
        out, NUM_ACTIONS * ACTION_BINS, ACTION_BINS,
        BATCH, ACTION_BINS, DIM, /*act=*/2);
}

// Round 2
// 651.988 us; speedup vs baseline: 2.0254x; 2.0254x over previous
//
#include <hip/hip_runtime.h>
#include <hip/hip_bf16.h>
#include <math.h>

#define DIM 1024
#define NUM_ACTIONS 8
#define ACTION_BINS 256
#define D_STATE 16
#define D_CONV 4
#define D_INNER 2048
#define DT_RANK 64
#define BATCH 512
#define SEQ 64
#define NTOK (BATCH * NUM_ACTIONS)   // 4096 tokens

typedef __attribute__((ext_vector_type(8))) short short8;
typedef __attribute__((ext_vector_type(4))) float floatx4;

// round-to-nearest-even f32 -> bf16 bit pattern (finite inputs)
__device__ __forceinline__ unsigned short f2bf(float f) {
    unsigned int u = __float_as_uint(f);
    unsigned int rnd = 0x7fffu + ((u >> 16) & 1u);
    return (unsigned short)((u + rnd) >> 16);
}

// async global->LDS, 16B per lane; LDS dst = wave-uniform base + lane*16
__device__ __forceinline__ void async_ld16(const void* g, void* l) {
    __builtin_amdgcn_global_load_lds(
        (const __attribute__((address_space(1))) void*)g,
        (__attribute__((address_space(3))) void*)l, 16, 0, 0);
}

// ---------------------------------------------------------------------------
// sos = mean over sequence -> tokens_bf[:, 0, :]  (bf16)
// ---------------------------------------------------------------------------
__global__ __launch_bounds__(256)
void sos_mean_kernel(const float* __restrict__ enc, unsigned short* __restrict__ tok) {
    int b = blockIdx.y;
    int d = blockIdx.x * 256 + threadIdx.x;
    const float* p = enc + (size_t)b * SEQ * DIM + d;
    float acc = 0.f;
#pragma unroll 8
    for (int s = 0; s < SEQ; ++s) acc += p[(size_t)s * DIM];
    tok[(size_t)b * NUM_ACTIONS * DIM + d] = f2bf(acc * (1.0f / SEQ));
}

// ---------------------------------------------------------------------------
// gather action-bin embeddings -> tokens_bf[:, 1+i, :]  (bf16)
// ---------------------------------------------------------------------------
__global__ __launch_bounds__(256)
void gather_tokens_kernel(const int* __restrict__ actions,
                          const float* __restrict__ abe,
                          unsigned short* __restrict__ tok) {
    int b = blockIdx.x;
    int i = blockIdx.y;  // 0..6
    int a = actions[b * (NUM_ACTIONS - 1) + i];
    float4 v = ((const float4*)(abe + ((size_t)i * ACTION_BINS + a) * DIM))[threadIdx.x];
    ushort4 o;
    o.x = f2bf(v.x); o.y = f2bf(v.y); o.z = f2bf(v.z); o.w = f2bf(v.w);
    ((ushort4*)(tok + ((size_t)b * NUM_ACTIONS + 1 + i) * DIM))[threadIdx.x] = o;
}

// ---------------------------------------------------------------------------
// f32 -> bf16 bulk convert (float4 -> ushort4), n4 = n/4
// ---------------------------------------------------------------------------
__global__ __launch_bounds__(256)
void cvt_f32_bf16(const float* __restrict__ in, unsigned short* __restrict__ out, int n4) {
    int i = blockIdx.x * 256 + threadIdx.x;
    if (i >= n4) return;
    float4 v = ((const float4*)in)[i];
    ushort4 o;
    o.x = f2bf(v.x); o.y = f2bf(v.y); o.z = f2bf(v.z); o.w = f2bf(v.w);
    ((ushort4*)out)[i] = o;
}

// ---------------------------------------------------------------------------
// bf16 MFMA GEMM (m97 structure): out[M,N] = A[M,K] * W[N,K]^T
// 128x128 tile, BK=32, 256 threads = 4 waves, each wave a 64x64 quadrant of
// 4x4 mfma_f32_16x16x32_bf16 tiles. LDS layout kseg-major so both the
// global_load_lds staging (wave-uniform base + lane*16) and the ds_read_b128
// fragment reads are lane-contiguous (conflict-free).
// MODE: 0 = f32 out, 1 = bf16 out, 2 = sigmoid f32 out. ROLL: W row r->(r+1)%N.
// Requires M%128==0, N%128==0, K%32==0, lda/ldw multiples of 8.
// ---------------------------------------------------------------------------
template <int MODE, int ROLL>
__global__ __launch_bounds__(256)
void gemm_mfma(const unsigned short* __restrict__ A, int lda, long long aStride,
               const unsigned short* __restrict__ W, int ldw, long long wStride,
               void* __restrict__ outv, int ldo, long long oStride,
               int N, int K) {
    __shared__ alignas(16) unsigned short As[4096];  // 4 kseg x 128 rows x 8
    __shared__ alignas(16) unsigned short Bs[4096];

    A += (size_t)blockIdx.z * aStride;
    W += (size_t)blockIdx.z * wStride;

    int tid = threadIdx.x;
    int w = tid >> 6, l = tid & 63;
    int q = l >> 4, lan = l & 15;
    int m0 = blockIdx.x * 128, n0 = blockIdx.y * 128;
    int wm = (w >> 1) * 64, wn = (w & 1) * 64;

    int rB0 = n0 + l, rB1 = n0 + 64 + l;
    if (ROLL) { rB0 = (rB0 + 1) % N; rB1 = (rB1 + 1) % N; }

    // wave w stages kseg=w for rows [0,64) and [64,128) of each tile
    const unsigned short* gA0 = A + (size_t)(m0 + l) * lda + w * 8;
    const unsigned short* gA1 = A + (size_t)(m0 + 64 + l) * lda + w * 8;
    const unsigned short* gB0 = W + (size_t)rB0 * ldw + w * 8;
    const unsigned short* gB1 = W + (size_t)rB1 * ldw + w * 8;
    unsigned short* lA0 = &As[(2 * w + 0) * 512];
    unsigned short* lA1 = &As[(2 * w + 1) * 512];
    unsigned short* lB0 = &Bs[(2 * w + 0) * 512];
    unsigned short* lB1 = &Bs[(2 * w + 1) * 512];

    floatx4 acc[4][4];
#pragma unroll
    for (int mi = 0; mi < 4; ++mi)
#pragma unroll
        for (int ni = 0; ni < 4; ++ni) acc[mi][ni] = (floatx4){0.f, 0.f, 0.f, 0.f};

    const int aoff = q * 1024 + (wm + lan) * 8;
    const int boff = q * 1024 + (wn + lan) * 8;

    for (int k0 = 0; k0 < K; k0 += 32) {
        async_ld16(gA0, lA0); async_ld16(gA1, lA1);
        async_ld16(gB0, lB0); async_ld16(gB1, lB1);
        gA0 += 32; gA1 += 32; gB0 += 32; gB1 += 32;
        __syncthreads();   // compiler emits vmcnt(0) drain before barrier

        short8 a[4], b[4];
#pragma unroll
        for (int i = 0; i < 4; ++i) a[i] = *(const short8*)&As[aoff + i * 128];
#pragma unroll
        for (int i = 0; i < 4; ++i) b[i] = *(const short8*)&Bs[boff + i * 128];
#pragma unroll
        for (int mi = 0; mi < 4; ++mi)
#pragma unroll
            for (int ni = 0; ni < 4; ++ni)
                acc[mi][ni] = __builtin_amdgcn_mfma_f32_16x16x32_bf16(
                    a[mi], b[ni], acc[mi][ni], 0, 0, 0);
        __syncthreads();
    }

    // Epilogue: C/D map col=lane&15, row=(lane>>4)*4+reg
    size_t obase = (size_t)blockIdx.z * oStride;
#pragma unroll
    for (int mi = 0; mi < 4; ++mi) {
#pragma unroll
        for (int r = 0; r < 4; ++r) {
            int mo = m0 + wm + mi * 16 + q * 4 + r;
            size_t rowo = obase + (size_t)mo * ldo;
#pragma unroll
            for (int ni = 0; ni < 4; ++ni) {
                int no = n0 + wn + ni * 16 + lan;
                float v = acc[mi][ni][r];
                if (MODE == 0) {
                    ((float*)outv)[rowo + no] = v;
                } else if (MODE == 1) {
                    ((unsigned short*)outv)[rowo + no] = f2bf(v);
                } else {
                    ((float*)outv)[rowo + no] = 1.0f / (1.0f + __expf(-v));
                }
            }
        }
    }
}

// ---------------------------------------------------------------------------
// fp32 tiled GEMM (kept for the small x_proj / dt_proj GEMMs)
// out[M,N] = act(A[M,K] * W[N,K]^T + bias)
// ---------------------------------------------------------------------------
template <int TM, int TN>
__global__ __launch_bounds__(256)
void gemm_bt(const float* __restrict__ A, int lda,
             const float* __restrict__ W, int ldw,
             const float* __restrict__ bias,
             float* __restrict__ out, int ldo,
             int M, int N, int K, int act) {
    constexpr int TK = 16;
    constexpr int GM = TM / 64;
    constexpr int GN = TN / 64;
    __shared__ float As[TK][TM + 4];
    __shared__ float Ws[TK][TN + 4];

    int tid = threadIdx.x;
    int tx = tid & 15, ty = tid >> 4;
    int m0 = blockIdx.x * TM, n0 = blockIdx.y * TN;

    float acc[GM * 4][GN * 4];
#pragma unroll
    for (int i = 0; i < GM * 4; ++i)
#pragma unroll
        for (int j = 0; j < GN * 4; ++j) acc[i][j] = 0.f;

    for (int k0 = 0; k0 < K; k0 += TK) {
#pragma unroll
        for (int l = 0; l < TM / 64; ++l) {
            int idx = tid + l * 256;
            int r = idx >> 2;
            int kk = (idx & 3) << 2;
            float4 v = make_float4(0.f, 0.f, 0.f, 0.f);
            int gr = m0 + r;
            if (gr < M) v = *(const float4*)(A + (size_t)gr * lda + k0 + kk);
            As[kk + 0][r] = v.x; As[kk + 1][r] = v.y;
            As[kk + 2][r] = v.z; As[kk + 3][r] = v.w;
        }
#pragma unroll
        for (int l = 0; l < TN / 64; ++l) {
            int idx = tid + l * 256;
            int r = idx >> 2;
            int kk = (idx & 3) << 2;
            int wr = n0 + r;
            float4 v = make_float4(0.f, 0.f, 0.f, 0.f);
            if (wr < N) v = *(const float4*)(W + (size_t)wr * ldw + k0 + kk);
            Ws[kk + 0][r] = v.x; Ws[kk + 1][r] = v.y;
            Ws[kk + 2][r] = v.z; Ws[kk + 3][r] = v.w;
        }
        __syncthreads();

#pragma unroll
        for (int k = 0; k < TK; ++k) {
            float a[GM * 4], bb[GN * 4];
#pragma unroll
            for (int g = 0; g < GM; ++g) {
                float4 v = *(const float4*)&As[k][g * 64 + ty * 4];
                a[g * 4 + 0] = v.x; a[g * 4 + 1] = v.y;
                a[g * 4 + 2] = v.z; a[g * 4 + 3] = v.w;
            }
#pragma unroll
            for (int g = 0; g < GN; ++g) {
                float4 v = *(const float4*)&Ws[k][g * 64 + tx * 4];
                bb[g * 4 + 0] = v.x; bb[g * 4 + 1] = v.y;
                bb[g * 4 + 2] = v.z; bb[g * 4 + 3] = v.w;
            }
#pragma unroll
            for (int i = 0; i < GM * 4; ++i)
#pragma unroll
                for (int j = 0; j < GN * 4; ++j)
                    acc[i][j] += a[i] * bb[j];
        }
        __syncthreads();
    }

#pragma unroll
    for (int i = 0; i < GM * 4; ++i) {
        int m = m0 + (i >> 2) * 64 + ty * 4 + (i & 3);
        if (m >= M) continue;
#pragma unroll
        for (int j = 0; j < GN * 4; ++j) {
            int n = n0 + (j >> 2) * 64 + tx * 4 + (j & 3);
            if (n >= N) continue;
            float v = acc[i][j];
            if (bias) v += bias[n];
            if (act == 1) v = (v > 20.0f) ? v : log1pf(__expf(v));   // softplus
            out[(size_t)m * ldo + n] = v;
        }
    }
}

// ---------------------------------------------------------------------------
// causal depthwise conv1d (k=4) + bias + SiLU; xh = xz[:, :D_INNER]
// ---------------------------------------------------------------------------
__global__ __launch_bounds__(256)
void conv_silu_kernel(const float* __restrict__ xz, const float* __restrict__ conv_w,
                      const float* __restrict__ conv_b, float* __restrict__ xc) {
    int c = blockIdx.x * 256 + threadIdx.x;
    int b = blockIdx.y;
    float4 w = *(const float4*)(conv_w + (size_t)c * 4);
    float bias = conv_b[c];
    const float* px = xz + (size_t)b * NUM_ACTIONS * (2 * D_INNER) + c;
    float x[NUM_ACTIONS];
#pragma unroll
    for (int t = 0; t < NUM_ACTIONS; ++t) x[t] = px[(size_t)t * (2 * D_INNER)];
    float* po = xc + (size_t)b * NUM_ACTIONS * D_INNER + c;
#pragma unroll
    for (int t = 0; t < NUM_ACTIONS; ++t) {
        float s = bias + x[t] * w.w;
        if (t >= 1) s += x[t - 1] * w.z;
        if (t >= 2) s += x[t - 2] * w.y;
        if (t >= 3) s += x[t - 3] * w.x;
        po[(size_t)t * D_INNER] = s * (1.0f / (1.0f + __expf(-s)));  // SiLU
    }
}

// ---------------------------------------------------------------------------
// selective scan (l=8) fused with y*silu(z); delta lives in xz[:, :2048],
// z in xz[:, 2048:]; writes ys as bf16.
// ---------------------------------------------------------------------------
__global__ __launch_bounds__(256)
void scan_kernel(const float* __restrict__ u_, const float* __restrict__ xz,
                 const float* __restrict__ x_dbl, const float* __restrict__ A_log,
                 const float* __restrict__ Dp, unsigned short* __restrict__ ys_bf) {
    int b = blockIdx.y;
    int d = blockIdx.x * 256 + threadIdx.x;
    __shared__ float Bs[NUM_ACTIONS][D_STATE], Cs[NUM_ACTIONS][D_STATE];
    int tid = threadIdx.x;
    if (tid < 128) {
        int t = tid >> 4, n = tid & 15;
        Bs[t][n] = x_dbl[(size_t)(b * NUM_ACTIONS + t) * 96 + 64 + n];
    } else {
        int qq = tid - 128;
        int t = qq >> 4, n = qq & 15;
        Cs[t][n] = x_dbl[(size_t)(b * NUM_ACTIONS + t) * 96 + 80 + n];
    }
    __syncthreads();

    float Av[D_STATE];
#pragma unroll
    for (int n = 0; n < D_STATE; ++n) Av[n] = -__expf(A_log[(size_t)d * D_STATE + n]);
    float Dv = Dp[d];
    float h[D_STATE];
#pragma unroll
    for (int n = 0; n < D_STATE; ++n) h[n] = 0.f;

#pragma unroll
    for (int t = 0; t < NUM_ACTIONS; ++t) {
        size_t tok = (size_t)(b * NUM_ACTIONS + t);
        float dt = xz[tok * (2 * D_INNER) + d];               // delta (stored in xh half)
        float uu = u_[tok * D_INNER + d];
        float zz = xz[tok * (2 * D_INNER) + D_INNER + d];     // z
        float du = dt * uu;
        float y = uu * Dv;
#pragma unroll
        for (int n = 0; n < D_STATE; ++n) {
            h[n] = __expf(dt * Av[n]) * h[n] + du * Bs[t][n];
            y += h[n] * Cs[t][n];
        }
        float sz = zz * (1.0f / (1.0f + __expf(-zz)));
        ys_bf[tok * D_INNER + d] = f2bf(y * sz);
    }
}

// ---------------------------------------------------------------------------
extern "C" void kernel_launch(void* const* d_in, const int* in_sizes, int n_in,
                              void* d_out, int out_size, void* d_ws, size_t ws_size,
                              hipStream_t stream) {
    const float* enc        = (const float*)d_in[0];
    const int*   actions    = (const int*)d_in[1];
    const float* abe        = (const float*)d_in[2];
    const float* in_proj_w  = (const float*)d_in[4];
    const float* conv_w     = (const float*)d_in[5];
    const float* conv_b     = (const float*)d_in[6];
    const float* x_proj_w   = (const float*)d_in[7];
    const float* dt_proj_w  = (const float*)d_in[8];
    const float* dt_proj_b  = (const float*)d_in[9];
    const float* A_log      = (const float*)d_in[10];
    const float* D_param    = (const float*)d_in[11];
    const float* out_proj_w = (const float*)d_in[12];
    float* out = (float*)d_out;

    // workspace layout (152.6 MB total)
    float* xz    = (float*)d_ws;                    // [4096,4096] xh||z; delta overwrites xh
    float* xc    = xz + (size_t)NTOK * 2 * D_INNER; // [4096,2048] u
    float* x_dbl = xc + (size_t)NTOK * D_INNER;     // [4096,96]
    unsigned short* tok_bf  = (unsigned short*)(x_dbl + (size_t)NTOK * 96); // [4096,1024]
    unsigned short* inw_bf  = tok_bf + (size_t)NTOK * DIM;                  // [4096,1024]
    unsigned short* outw_bf = inw_bf + (size_t)(2 * D_INNER) * DIM;         // [1024,2048]
    unsigned short* abe_bf  = outw_bf + (size_t)DIM * D_INNER;              // [8,256,1024]
    unsigned short* ys_bf   = abe_bf + (size_t)NUM_ACTIONS * ACTION_BINS * DIM; // [4096,2048]
    unsigned short* emb_bf  = ys_bf + (size_t)NTOK * D_INNER;               // [4096,1024]

    // 1) tokens (bf16) + weight conversions
    sos_mean_kernel<<<dim3(DIM / 256, BATCH), 256, 0, stream>>>(enc, tok_bf);
    gather_tokens_kernel<<<dim3(BATCH, NUM_ACTIONS - 1), 256, 0, stream>>>(actions, abe, tok_bf);
    {
        int n4 = (2 * D_INNER * DIM) / 4;
        cvt_f32_bf16<<<(n4 + 255) / 256, 256, 0, stream>>>(in_proj_w, inw_bf, n4);
        n4 = (DIM * D_INNER) / 4;
        cvt_f32_bf16<<<(n4 + 255) / 256, 256, 0, stream>>>(out_proj_w, outw_bf, n4);
        n4 = (NUM_ACTIONS * ACTION_BINS * DIM) / 4;
        cvt_f32_bf16<<<(n4 + 255) / 256, 256, 0, stream>>>(abe, abe_bf, n4);
    }

    // 2) in_proj (MFMA): xz[4096,4096] = tokens @ in_proj_w^T
    gemm_mfma<0, 0><<<dim3(NTOK / 128, (2 * D_INNER) / 128, 1), 256, 0, stream>>>(
        tok_bf, DIM, 0, inw_bf, DIM, 0, xz, 2 * D_INNER, 0, 2 * D_INNER, DIM);

    // 3) conv + silu -> xc (u)
    conv_silu_kernel<<<dim3(D_INNER / 256, BATCH), 256, 0, stream>>>(xz, conv_w, conv_b, xc);

    // 4) x_proj (fp32): x_dbl[4096,96] = xc @ x_proj_w^T
    gemm_bt<64, 64><<<dim3(NTOK / 64, 2), 256, 0, stream>>>(
        xc, D_INNER, x_proj_w, D_INNER, nullptr, x_dbl, 96, NTOK, 96, D_INNER, 0);

    // 5) delta = softplus(x_dbl[:,:64] @ dt_proj_w^T + b) -> xz[:, :2048] (xh is dead)
    gemm_bt<64, 64><<<dim3(NTOK / 64, D_INNER / 64), 256, 0, stream>>>(
        x_dbl, 96, dt_proj_w, DT_RANK, dt_proj_b, xz, 2 * D_INNER, NTOK, D_INNER, DT_RANK, 1);

    // 6) selective scan + y*silu(z) -> ys_bf
    scan_kernel<<<dim3(D_INNER / 256, BATCH), 256, 0, stream>>>(
        xc, xz, x_dbl, A_log, D_param, ys_bf);

    // 7) out_proj (MFMA): emb_bf[4096,1024] = ys @ out_proj_w^T
    gemm_mfma<1, 0><<<dim3(NTOK / 128, DIM / 128, 1), 256, 0, stream>>>(
        ys_bf, D_INNER, 0, outw_bf, D_INNER, 0, emb_bf, DIM, 0, DIM, D_INNER);

    // 8) logits (MFMA, batched over 8 action slots, rolled W, sigmoid epilogue)
    gemm_mfma<2, 1><<<dim3(BATCH / 128, ACTION_BINS / 128, NUM_ACTIONS), 256, 0, stream>>>(
        emb_bf, NUM_ACTIONS * DIM, DIM,
        abe_bf, DIM, (long long)ACTION_BINS * DIM,
        out, NUM_ACTIONS * ACTION_BINS, ACTION_BINS,
        ACTION_BINS, DIM);
}

// Round 3
// 544.779 us; speedup vs baseline: 2.4240x; 1.1968x over previous
//
#include <hip/hip_runtime.h>
#include <hip/hip_bf16.h>
#include <math.h>

#define DIM 1024
#define NUM_ACTIONS 8
#define ACTION_BINS 256
#define D_STATE 16
#define D_CONV 4
#define D_INNER 2048
#define DT_RANK 64
#define BATCH 512
#define SEQ 64
#define NTOK (BATCH * NUM_ACTIONS)   // 4096 tokens

typedef __attribute__((ext_vector_type(8))) short short8;
typedef __attribute__((ext_vector_type(4))) float floatx4;

// round-to-nearest-even f32 -> bf16 bit pattern (finite inputs)
__device__ __forceinline__ unsigned short f2bf(float f) {
    unsigned int u = __float_as_uint(f);
    unsigned int rnd = 0x7fffu + ((u >> 16) & 1u);
    return (unsigned short)((u + rnd) >> 16);
}
__device__ __forceinline__ float bf2f(unsigned short v) {
    return __uint_as_float(((unsigned int)v) << 16);
}

// async global->LDS, 16B per lane; LDS dst = wave-uniform base + lane*16
__device__ __forceinline__ void async_ld16(const void* g, void* l) {
    __builtin_amdgcn_global_load_lds(
        (const __attribute__((address_space(1))) void*)g,
        (__attribute__((address_space(3))) void*)l, 16, 0, 0);
}

// ---------------------------------------------------------------------------
// sos = mean over sequence -> tokens_bf[:, 0, :]  (bf16)
// ---------------------------------------------------------------------------
__global__ __launch_bounds__(256)
void sos_mean_kernel(const float* __restrict__ enc, unsigned short* __restrict__ tok) {
    int b = blockIdx.y;
    int d = blockIdx.x * 256 + threadIdx.x;
    const float* p = enc + (size_t)b * SEQ * DIM + d;
    float acc = 0.f;
#pragma unroll 8
    for (int s = 0; s < SEQ; ++s) acc += p[(size_t)s * DIM];
    tok[(size_t)b * NUM_ACTIONS * DIM + d] = f2bf(acc * (1.0f / SEQ));
}

// ---------------------------------------------------------------------------
// gather action-bin embeddings -> tokens_bf[:, 1+i, :]  (bf16)
// ---------------------------------------------------------------------------
__global__ __launch_bounds__(256)
void gather_tokens_kernel(const int* __restrict__ actions,
                          const float* __restrict__ abe,
                          unsigned short* __restrict__ tok) {
    int b = blockIdx.x;
    int i = blockIdx.y;  // 0..6
    int a = actions[b * (NUM_ACTIONS - 1) + i];
    float4 v = ((const float4*)(abe + ((size_t)i * ACTION_BINS + a) * DIM))[threadIdx.x];
    ushort4 o;
    o.x = f2bf(v.x); o.y = f2bf(v.y); o.z = f2bf(v.z); o.w = f2bf(v.w);
    ((ushort4*)(tok + ((size_t)b * NUM_ACTIONS + 1 + i) * DIM))[threadIdx.x] = o;
}

// ---------------------------------------------------------------------------
// f32 -> bf16 bulk convert (float4 -> ushort4), n4 = n/4
// ---------------------------------------------------------------------------
__global__ __launch_bounds__(256)
void cvt_f32_bf16(const float* __restrict__ in, unsigned short* __restrict__ out, int n4) {
    int i = blockIdx.x * 256 + threadIdx.x;
    if (i >= n4) return;
    float4 v = ((const float4*)in)[i];
    ushort4 o;
    o.x = f2bf(v.x); o.y = f2bf(v.y); o.z = f2bf(v.z); o.w = f2bf(v.w);
    ((ushort4*)out)[i] = o;
}

// x_proj_w [96,2048] f32 -> [128,2048] bf16 zero-padded
__global__ __launch_bounds__(256)
void cvt_pad_xpw(const float* __restrict__ in, unsigned short* __restrict__ out) {
    int i = blockIdx.x * 256 + threadIdx.x;   // over 128*2048/4 = 65536
    int row = i >> 9;                          // 512 float4 per row
    ushort4 o; o.x = o.y = o.z = o.w = 0;
    if (row < 96) {
        float4 v = ((const float4*)in)[i];
        o.x = f2bf(v.x); o.y = f2bf(v.y); o.z = f2bf(v.z); o.w = f2bf(v.w);
    }
    ((ushort4*)out)[i] = o;
}

// x_dbl[:, 0:64] (stride 96, f32) -> dt_bf [4096,64] bf16
__global__ __launch_bounds__(256)
void cvt_dt(const float* __restrict__ x_dbl, unsigned short* __restrict__ dt_bf) {
    int i = blockIdx.x * 256 + threadIdx.x;   // over 4096*16 = 65536
    int row = i >> 4, c4 = i & 15;
    float4 v = *(const float4*)(x_dbl + (size_t)row * 96 + c4 * 4);
    ushort4 o;
    o.x = f2bf(v.x); o.y = f2bf(v.y); o.z = f2bf(v.z); o.w = f2bf(v.w);
    ((ushort4*)dt_bf)[i] = o;
}

// ---------------------------------------------------------------------------
// bf16 MFMA GEMM (m97 structure): out[M,N] = A[M,K] * W[N,K]^T
// 128x128 tile, BK=32, 4 waves each owning a 64x64 quadrant of 4x4 16x16x32
// MFMAs. LDS kseg-major: staging is wave-uniform-base+lane*16, fragment reads
// are lane-contiguous ds_read_b128.
// MODE 1: bf16 out
// MODE 2: sigmoid f32 out, W row rolled r->(r+1)%N
// MODE 4: split-K; blockIdx.z selects K-chunk [z*K,(z+1)*K); fp32 atomicAdd
//         into out (cols < Nout only)
// MODE 5: in_proj fused: cols [0,2048) -> f32 out1 (xh), cols [2048,4096) ->
//         bf16 silu -> out2 (zs), both ldo=2048
// MODE 6: bias + softplus + bf16 out
// ---------------------------------------------------------------------------
template <int MODE>
__global__ __launch_bounds__(256)
void gemm_mfma(const unsigned short* __restrict__ A, int lda, long long aStride,
               const unsigned short* __restrict__ W, int ldw, long long wStride,
               const float* __restrict__ bias,
               void* __restrict__ out1, void* __restrict__ out2,
               int ldo, long long oStride, int N, int K, int Nout) {
    __shared__ alignas(16) unsigned short As[4096];  // 4 kseg x 128 rows x 8
    __shared__ alignas(16) unsigned short Bs[4096];

    long long kbase = 0;
    if (MODE == 4) {
        kbase = (long long)blockIdx.z * K;
    } else {
        A += (size_t)blockIdx.z * aStride;
        W += (size_t)blockIdx.z * wStride;
    }

    int tid = threadIdx.x;
    int w = tid >> 6, l = tid & 63;
    int q = l >> 4, lan = l & 15;
    int m0 = blockIdx.x * 128, n0 = blockIdx.y * 128;
    int wm = (w >> 1) * 64, wn = (w & 1) * 64;

    int rB0 = n0 + l, rB1 = n0 + 64 + l;
    if (MODE == 2) { rB0 = (rB0 + 1) % N; rB1 = (rB1 + 1) % N; }

    const unsigned short* gA0 = A + (size_t)(m0 + l) * lda + kbase + w * 8;
    const unsigned short* gA1 = A + (size_t)(m0 + 64 + l) * lda + kbase + w * 8;
    const unsigned short* gB0 = W + (size_t)rB0 * ldw + kbase + w * 8;
    const unsigned short* gB1 = W + (size_t)rB1 * ldw + kbase + w * 8;
    unsigned short* lA0 = &As[(2 * w + 0) * 512];
    unsigned short* lA1 = &As[(2 * w + 1) * 512];
    unsigned short* lB0 = &Bs[(2 * w + 0) * 512];
    unsigned short* lB1 = &Bs[(2 * w + 1) * 512];

    floatx4 acc[4][4];
#pragma unroll
    for (int mi = 0; mi < 4; ++mi)
#pragma unroll
        for (int ni = 0; ni < 4; ++ni) acc[mi][ni] = (floatx4){0.f, 0.f, 0.f, 0.f};

    const int aoff = q * 1024 + (wm + lan) * 8;
    const int boff = q * 1024 + (wn + lan) * 8;

    for (int k0 = 0; k0 < K; k0 += 32) {
        async_ld16(gA0, lA0); async_ld16(gA1, lA1);
        async_ld16(gB0, lB0); async_ld16(gB1, lB1);
        gA0 += 32; gA1 += 32; gB0 += 32; gB1 += 32;
        __syncthreads();

        short8 a[4], b[4];
#pragma unroll
        for (int i = 0; i < 4; ++i) a[i] = *(const short8*)&As[aoff + i * 128];
#pragma unroll
        for (int i = 0; i < 4; ++i) b[i] = *(const short8*)&Bs[boff + i * 128];
#pragma unroll
        for (int mi = 0; mi < 4; ++mi)
#pragma unroll
            for (int ni = 0; ni < 4; ++ni)
                acc[mi][ni] = __builtin_amdgcn_mfma_f32_16x16x32_bf16(
                    a[mi], b[ni], acc[mi][ni], 0, 0, 0);
        __syncthreads();
    }

    // Epilogue: C/D map col=lane&15, row=(lane>>4)*4+reg
    size_t obase = (size_t)blockIdx.z * oStride;
#pragma unroll
    for (int mi = 0; mi < 4; ++mi) {
#pragma unroll
        for (int r = 0; r < 4; ++r) {
            int mo = m0 + wm + mi * 16 + q * 4 + r;
#pragma unroll
            for (int ni = 0; ni < 4; ++ni) {
                int no = n0 + wn + ni * 16 + lan;
                float v = acc[mi][ni][r];
                if (MODE == 1) {
                    ((unsigned short*)out1)[obase + (size_t)mo * ldo + no] = f2bf(v);
                } else if (MODE == 2) {
                    ((float*)out1)[obase + (size_t)mo * ldo + no] =
                        1.0f / (1.0f + __expf(-v));
                } else if (MODE == 4) {
                    if (no < Nout)
                        atomicAdd(&((float*)out1)[(size_t)mo * ldo + no], v);
                } else if (MODE == 5) {
                    if (no < D_INNER) {
                        ((float*)out1)[(size_t)mo * D_INNER + no] = v;
                    } else {
                        float s = v / (1.0f + __expf(-v));   // silu(z)
                        ((unsigned short*)out2)[(size_t)mo * D_INNER + no - D_INNER] = f2bf(s);
                    }
                } else if (MODE == 6) {
                    float x = v + bias[no];
                    float s = (x > 20.0f) ? x : log1pf(__expf(x));  // softplus
                    ((unsigned short*)out1)[obase + (size_t)mo * ldo + no] = f2bf(s);
                }
            }
        }
    }
}

// ---------------------------------------------------------------------------
// causal depthwise conv1d (k=4) + bias + SiLU: xh f32 [NTOK,D_INNER] ->
// xc_bf bf16 [NTOK,D_INNER]
// ---------------------------------------------------------------------------
__global__ __launch_bounds__(256)
void conv_silu_kernel(const float* __restrict__ xh, const float* __restrict__ conv_w,
                      const float* __restrict__ conv_b, unsigned short* __restrict__ xc_bf) {
    int c = blockIdx.x * 256 + threadIdx.x;
    int b = blockIdx.y;
    float4 w = *(const float4*)(conv_w + (size_t)c * 4);
    float bias = conv_b[c];
    const float* px = xh + (size_t)b * NUM_ACTIONS * D_INNER + c;
    float x[NUM_ACTIONS];
#pragma unroll
    for (int t = 0; t < NUM_ACTIONS; ++t) x[t] = px[(size_t)t * D_INNER];
    unsigned short* po = xc_bf + (size_t)b * NUM_ACTIONS * D_INNER + c;
#pragma unroll
    for (int t = 0; t < NUM_ACTIONS; ++t) {
        float s = bias + x[t] * w.w;
        if (t >= 1) s += x[t - 1] * w.z;
        if (t >= 2) s += x[t - 2] * w.y;
        if (t >= 3) s += x[t - 3] * w.x;
        po[(size_t)t * D_INNER] = f2bf(s * (1.0f / (1.0f + __expf(-s))));  // SiLU
    }
}

// ---------------------------------------------------------------------------
// selective scan (l=8): u=xc_bf, delta=delta_bf, B/C from x_dbl via UNIFORM
// scalar loads (SGPR broadcast — no LDS), z=zs_bf (silu pre-applied).
// ys_bf = y * silu(z) in bf16. grid (D_INNER/256, BATCH)
// ---------------------------------------------------------------------------
__global__ __launch_bounds__(256)
void scan_kernel(const unsigned short* __restrict__ u_bf,
                 const unsigned short* __restrict__ zs_bf,
                 const unsigned short* __restrict__ delta_bf,
                 const float* __restrict__ x_dbl,
                 const float* __restrict__ A_log, const float* __restrict__ Dp,
                 unsigned short* __restrict__ ys_bf) {
    int b = blockIdx.y;
    int d = blockIdx.x * 256 + threadIdx.x;

    float Av[D_STATE];
    {
        const float4* a4 = (const float4*)(A_log + (size_t)d * D_STATE);
#pragma unroll
        for (int i = 0; i < 4; ++i) {
            float4 v = a4[i];
            Av[4 * i + 0] = -__expf(v.x); Av[4 * i + 1] = -__expf(v.y);
            Av[4 * i + 2] = -__expf(v.z); Av[4 * i + 3] = -__expf(v.w);
        }
    }
    float Dv = Dp[d];
    float h[D_STATE];
#pragma unroll
    for (int n = 0; n < D_STATE; ++n) h[n] = 0.f;

    const float* xd = x_dbl + (size_t)b * NUM_ACTIONS * 96;   // uniform base
#pragma unroll
    for (int t = 0; t < NUM_ACTIONS; ++t) {
        size_t tok = (size_t)(b * NUM_ACTIONS + t);
        float dt = bf2f(delta_bf[tok * D_INNER + d]);
        float uu = bf2f(u_bf[tok * D_INNER + d]);
        float sz = bf2f(zs_bf[tok * D_INNER + d]);
        float du = dt * uu;
        float y = uu * Dv;
#pragma unroll
        for (int n = 0; n < D_STATE; ++n) {
            // xd[...] are block-uniform -> scalar loads, SGPR operands
            h[n] = __expf(dt * Av[n]) * h[n] + du * xd[t * 96 + 64 + n];
            y += h[n] * xd[t * 96 + 80 + n];
        }
        ys_bf[tok * D_INNER + d] = f2bf(y * sz);
    }
}

// ---------------------------------------------------------------------------
extern "C" void kernel_launch(void* const* d_in, const int* in_sizes, int n_in,
                              void* d_out, int out_size, void* d_ws, size_t ws_size,
                              hipStream_t stream) {
    const float* enc        = (const float*)d_in[0];
    const int*   actions    = (const int*)d_in[1];
    const float* abe        = (const float*)d_in[2];
    const float* in_proj_w  = (const float*)d_in[4];
    const float* conv_w     = (const float*)d_in[5];
    const float* conv_b     = (const float*)d_in[6];
    const float* x_proj_w   = (const float*)d_in[7];
    const float* dt_proj_w  = (const float*)d_in[8];
    const float* dt_proj_b  = (const float*)d_in[9];
    const float* A_log      = (const float*)d_in[10];
    const float* D_param    = (const float*)d_in[11];
    const float* out_proj_w = (const float*)d_in[12];
    float* out = (float*)d_out;

    // workspace layout (~137 MB)
    char* p = (char*)d_ws;
    float* xh = (float*)p;                 p += (size_t)NTOK * D_INNER * 4;       // 33.6M
    float* x_dbl = (float*)p;              p += (size_t)NTOK * 96 * 4;            // 1.6M
    unsigned short* xc_bf = (unsigned short*)p;  p += (size_t)NTOK * D_INNER * 2; // 16.8M
    unsigned short* zs_bf = (unsigned short*)p;  p += (size_t)NTOK * D_INNER * 2; // 16.8M
    unsigned short* delta_bf = (unsigned short*)p; p += (size_t)NTOK * D_INNER * 2; // 16.8M
    unsigned short* ys_bf = (unsigned short*)p;  p += (size_t)NTOK * D_INNER * 2; // 16.8M
    unsigned short* tok_bf = (unsigned short*)p; p += (size_t)NTOK * DIM * 2;     // 8.4M
    unsigned short* emb_bf = (unsigned short*)p; p += (size_t)NTOK * DIM * 2;     // 8.4M
    unsigned short* inw_bf = (unsigned short*)p; p += (size_t)2 * D_INNER * DIM * 2; // 8.4M
    unsigned short* outw_bf = (unsigned short*)p; p += (size_t)DIM * D_INNER * 2; // 4.2M
    unsigned short* abe_bf = (unsigned short*)p; p += (size_t)NUM_ACTIONS * ACTION_BINS * DIM * 2; // 4.2M
    unsigned short* xpw_bf = (unsigned short*)p; p += (size_t)128 * D_INNER * 2;  // 0.5M
    unsigned short* dt_bf = (unsigned short*)p;  p += (size_t)NTOK * DT_RANK * 2; // 0.5M
    unsigned short* dtw_bf = (unsigned short*)p; p += (size_t)D_INNER * DT_RANK * 2; // 0.3M

    // 0) zero x_dbl for split-K atomics
    hipMemsetAsync(x_dbl, 0, (size_t)NTOK * 96 * 4, stream);

    // 1) tokens (bf16) + weight conversions
    sos_mean_kernel<<<dim3(DIM / 256, BATCH), 256, 0, stream>>>(enc, tok_bf);
    gather_tokens_kernel<<<dim3(BATCH, NUM_ACTIONS - 1), 256, 0, stream>>>(actions, abe, tok_bf);
    {
        int n4 = (2 * D_INNER * DIM) / 4;
        cvt_f32_bf16<<<(n4 + 255) / 256, 256, 0, stream>>>(in_proj_w, inw_bf, n4);
        n4 = (DIM * D_INNER) / 4;
        cvt_f32_bf16<<<(n4 + 255) / 256, 256, 0, stream>>>(out_proj_w, outw_bf, n4);
        n4 = (NUM_ACTIONS * ACTION_BINS * DIM) / 4;
        cvt_f32_bf16<<<(n4 + 255) / 256, 256, 0, stream>>>(abe, abe_bf, n4);
        n4 = (D_INNER * DT_RANK) / 4;
        cvt_f32_bf16<<<(n4 + 255) / 256, 256, 0, stream>>>(dt_proj_w, dtw_bf, n4);
        cvt_pad_xpw<<<256, 256, 0, stream>>>(x_proj_w, xpw_bf);
    }

    // 2) in_proj (MFMA, fused split epilogue): xh f32 + silu(z) bf16
    gemm_mfma<5><<<dim3(NTOK / 128, (2 * D_INNER) / 128, 1), 256, 0, stream>>>(
        tok_bf, DIM, 0, inw_bf, DIM, 0, nullptr,
        xh, zs_bf, D_INNER, 0, 2 * D_INNER, DIM, 0);

    // 3) conv + silu -> xc_bf (u)
    conv_silu_kernel<<<dim3(D_INNER / 256, BATCH), 256, 0, stream>>>(xh, conv_w, conv_b, xc_bf);

    // 4) x_proj (MFMA split-K over 8 chunks of 256): x_dbl += xc @ xpw^T
    gemm_mfma<4><<<dim3(NTOK / 128, 1, 8), 256, 0, stream>>>(
        xc_bf, D_INNER, 0, xpw_bf, D_INNER, 0, nullptr,
        x_dbl, nullptr, 96, 0, 128, D_INNER / 8, 96);

    // 5) dt ranks -> bf16; delta = softplus(dt @ dtw^T + b) (MFMA, bf16 out)
    cvt_dt<<<256, 256, 0, stream>>>(x_dbl, dt_bf);
    gemm_mfma<6><<<dim3(NTOK / 128, D_INNER / 128, 1), 256, 0, stream>>>(
        dt_bf, DT_RANK, 0, dtw_bf, DT_RANK, 0, dt_proj_b,
        delta_bf, nullptr, D_INNER, 0, D_INNER, DT_RANK, 0);

    // 6) selective scan + y*silu(z) -> ys_bf (B/C via scalar loads)
    scan_kernel<<<dim3(D_INNER / 256, BATCH), 256, 0, stream>>>(
        xc_bf, zs_bf, delta_bf, x_dbl, A_log, D_param, ys_bf);

    // 7) out_proj (MFMA): emb_bf = ys @ out_proj_w^T
    gemm_mfma<1><<<dim3(NTOK / 128, DIM / 128, 1), 256, 0, stream>>>(
        ys_bf, D_INNER, 0, outw_bf, D_INNER, 0, nullptr,
        emb_bf, nullptr, DIM, 0, DIM, D_INNER, 0);

    // 8) logits (MFMA, batched over 8 slots, rolled W, sigmoid)
    gemm_mfma<2><<<dim3(BATCH / 128, ACTION_BINS / 128, NUM_ACTIONS), 256, 0, stream>>>(
        emb_bf, NUM_ACTIONS * DIM, DIM,
        abe_bf, DIM, (long long)ACTION_BINS * DIM, nullptr,
        out, nullptr, NUM_ACTIONS * ACTION_BINS, ACTION_BINS,
        ACTION_BINS, DIM, 0);
}

// Round 4
// 515.211 us; speedup vs baseline: 2.5631x; 1.0574x over previous
//
#include <hip/hip_runtime.h>
#include <hip/hip_bf16.h>
#include <math.h>

#define DIM 1024
#define NUM_ACTIONS 8
#define ACTION_BINS 256
#define D_STATE 16
#define D_CONV 4
#define D_INNER 2048
#define DT_RANK 64
#define BATCH 512
#define SEQ 64
#define NTOK (BATCH * NUM_ACTIONS)   // 4096 tokens

typedef __attribute__((ext_vector_type(8))) short short8;
typedef __attribute__((ext_vector_type(4))) float floatx4;

// round-to-nearest-even f32 -> bf16 bit pattern (finite inputs)
__device__ __forceinline__ unsigned short f2bf(float f) {
    unsigned int u = __float_as_uint(f);
    unsigned int rnd = 0x7fffu + ((u >> 16) & 1u);
    return (unsigned short)((u + rnd) >> 16);
}
__device__ __forceinline__ float bf2f(unsigned short v) {
    return __uint_as_float(((unsigned int)v) << 16);
}

// async global->LDS, 16B per lane; LDS dst = wave-uniform base + lane*16
__device__ __forceinline__ void async_ld16(const void* g, void* l) {
    __builtin_amdgcn_global_load_lds(
        (const __attribute__((address_space(1))) void*)g,
        (__attribute__((address_space(3))) void*)l, 16, 0, 0);
}

// ---------------------------------------------------------------------------
// sos = mean over sequence -> tokens_bf[:, 0, :]  (bf16), float4 loads
// grid (1, BATCH): thread covers 4 d's
// ---------------------------------------------------------------------------
__global__ __launch_bounds__(256)
void sos_mean_kernel(const float* __restrict__ enc, unsigned short* __restrict__ tok) {
    int b = blockIdx.y;
    int d4 = threadIdx.x;                      // 256 float4 = 1024 floats
    const float4* p = (const float4*)(enc + (size_t)b * SEQ * DIM) + d4;
    float4 acc = make_float4(0.f, 0.f, 0.f, 0.f);
#pragma unroll 8
    for (int s = 0; s < SEQ; ++s) {
        float4 v = p[(size_t)s * (DIM / 4)];
        acc.x += v.x; acc.y += v.y; acc.z += v.z; acc.w += v.w;
    }
    ushort4 o;
    o.x = f2bf(acc.x * (1.0f / SEQ)); o.y = f2bf(acc.y * (1.0f / SEQ));
    o.z = f2bf(acc.z * (1.0f / SEQ)); o.w = f2bf(acc.w * (1.0f / SEQ));
    ((ushort4*)(tok + (size_t)b * NUM_ACTIONS * DIM))[d4] = o;
}

// ---------------------------------------------------------------------------
// gather action-bin embeddings -> tokens_bf[:, 1+i, :]  (bf16)
// ---------------------------------------------------------------------------
__global__ __launch_bounds__(256)
void gather_tokens_kernel(const int* __restrict__ actions,
                          const float* __restrict__ abe,
                          unsigned short* __restrict__ tok) {
    int b = blockIdx.x;
    int i = blockIdx.y;  // 0..6
    int a = actions[b * (NUM_ACTIONS - 1) + i];
    float4 v = ((const float4*)(abe + ((size_t)i * ACTION_BINS + a) * DIM))[threadIdx.x];
    ushort4 o;
    o.x = f2bf(v.x); o.y = f2bf(v.y); o.z = f2bf(v.z); o.w = f2bf(v.w);
    ((ushort4*)(tok + ((size_t)b * NUM_ACTIONS + 1 + i) * DIM))[threadIdx.x] = o;
}

// ---------------------------------------------------------------------------
// all weight conversions fused into one launch (f4-indexed segments)
// ---------------------------------------------------------------------------
#define SEG0 1048576                      // in_proj_w  [4096,1024]
#define SEG1 (SEG0 + 524288)              // out_proj_w [1024,2048]
#define SEG2 (SEG1 + 524288)              // abe        [8,256,1024]
#define SEG3 (SEG2 + 32768)               // dt_proj_w  [2048,64]
#define SEG4 (SEG3 + 65536)               // xpw padded [128,2048]

__device__ __forceinline__ void cvt4(const float* in, unsigned short* out, int i) {
    float4 v = ((const float4*)in)[i];
    ushort4 o;
    o.x = f2bf(v.x); o.y = f2bf(v.y); o.z = f2bf(v.z); o.w = f2bf(v.w);
    ((ushort4*)out)[i] = o;
}

__global__ __launch_bounds__(256)
void cvt_all(const float* __restrict__ inw, const float* __restrict__ outw,
             const float* __restrict__ abe, const float* __restrict__ dtw,
             const float* __restrict__ xpw,
             unsigned short* __restrict__ inw_bf, unsigned short* __restrict__ outw_bf,
             unsigned short* __restrict__ abe_bf, unsigned short* __restrict__ dtw_bf,
             unsigned short* __restrict__ xpw_bf) {
    int i = blockIdx.x * 256 + threadIdx.x;
    if (i < SEG0) { cvt4(inw, inw_bf, i); }
    else if (i < SEG1) { cvt4(outw, outw_bf, i - SEG0); }
    else if (i < SEG2) { cvt4(abe, abe_bf, i - SEG1); }
    else if (i < SEG3) { cvt4(dtw, dtw_bf, i - SEG2); }
    else if (i < SEG4) {
        int j = i - SEG3;
        int row = j >> 9;                  // 512 f4 per 2048-wide row
        ushort4 o; o.x = o.y = o.z = o.w = 0;
        if (row < 96) {
            float4 v = ((const float4*)xpw)[j];
            o.x = f2bf(v.x); o.y = f2bf(v.y); o.z = f2bf(v.z); o.w = f2bf(v.w);
        }
        ((ushort4*)xpw_bf)[j] = o;
    }
}

// x_dbl[:, 0:64] (stride 96, f32) -> dt_bf [4096,64] bf16
__global__ __launch_bounds__(256)
void cvt_dt(const float* __restrict__ x_dbl, unsigned short* __restrict__ dt_bf) {
    int i = blockIdx.x * 256 + threadIdx.x;   // over 4096*16 = 65536
    int row = i >> 4, c4 = i & 15;
    float4 v = *(const float4*)(x_dbl + (size_t)row * 96 + c4 * 4);
    ushort4 o;
    o.x = f2bf(v.x); o.y = f2bf(v.y); o.z = f2bf(v.z); o.w = f2bf(v.w);
    ((ushort4*)dt_bf)[i] = o;
}

// ---------------------------------------------------------------------------
// bf16 MFMA GEMM: out[M,N] = A[M,K] * W[N,K]^T
// 128x128 tile, BK=64, 4 waves each owning a 64x64 quadrant of 4x4 16x16x32
// MFMAs (2 k-substeps). LDS kseg-major (8 ksegs x 128 rows x 8 shorts).
// RGX/RGY: XCD-pinned L2 region swizzle (0 = off). Assumes workgroup->XCD is
// round-robin by flat block id % 8 (locality heuristic only; correctness-safe).
// Each region = RGX x RGY tiles handled by one XCD so the A-stripe + W-stripe
// stay resident in that XCD's 4 MB L2.
// MODE 1: bf16 out
// MODE 2: sigmoid f32 out, W row rolled r->(r+1)%N
// MODE 4: split-K over blockIdx.z; fp32 atomicAdd into out (cols < Nout)
// MODE 5: in_proj fused: cols [0,2048) -> bf16 xh (out1); [2048,4096) ->
//         bf16 silu(z) (out2), both ldo = 2048
// MODE 6: bias + softplus + bf16 out
// ---------------------------------------------------------------------------
template <int MODE, int RGX, int RGY>
__global__ __launch_bounds__(256)
void gemm_mfma(const unsigned short* __restrict__ A, int lda, long long aStride,
               const unsigned short* __restrict__ W, int ldw, long long wStride,
               const float* __restrict__ bias,
               void* __restrict__ out1, void* __restrict__ out2,
               int ldo, long long oStride, int N, int K, int Nout) {
    __shared__ alignas(16) unsigned short As[8192];  // 8 kseg x 128 rows x 8
    __shared__ alignas(16) unsigned short Bs[8192];

    int bx = blockIdx.x, by = blockIdx.y;
    if (RGX > 0) {
        int gx = gridDim.x;
        int id = by * gx + bx;
        constexpr int P = RGX * RGY;
        int xcd = id & 7;
        int h = id >> 3;
        int pos = h % P;
        int sup = h / P;
        int rgn = xcd + 8 * sup;
        int rgx_cnt = gx / RGX;
        int rm = rgn % rgx_cnt, rn = rgn / rgx_cnt;
        bx = rm * RGX + pos % RGX;
        by = rn * RGY + pos / RGX;
    }

    long long kbase = 0;
    if (MODE == 4) {
        kbase = (long long)blockIdx.z * K;
    } else {
        A += (size_t)blockIdx.z * aStride;
        W += (size_t)blockIdx.z * wStride;
    }

    int tid = threadIdx.x;
    int w = tid >> 6, l = tid & 63;
    int q = l >> 4, lan = l & 15;
    int m0 = bx * 128, n0 = by * 128;
    int wm = (w >> 1) * 64, wn = (w & 1) * 64;

    int rB0 = n0 + l, rB1 = n0 + 64 + l;
    if (MODE == 2) { rB0 = (rB0 + 1) % N; rB1 = (rB1 + 1) % N; }

    // wave w stages ksegs {w, w+4}; +32 shorts (=64B) folds into inst offset
    const unsigned short* gA0 = A + (size_t)(m0 + l) * lda + kbase + w * 8;
    const unsigned short* gA1 = A + (size_t)(m0 + 64 + l) * lda + kbase + w * 8;
    const unsigned short* gB0 = W + (size_t)rB0 * ldw + kbase + w * 8;
    const unsigned short* gB1 = W + (size_t)rB1 * ldw + kbase + w * 8;
    unsigned short* lA0a = &As[w * 1024 + l * 8];
    unsigned short* lA0b = &As[(w + 4) * 1024 + l * 8];
    unsigned short* lA1a = &As[w * 1024 + (64 + l) * 8];
    unsigned short* lA1b = &As[(w + 4) * 1024 + (64 + l) * 8];
    unsigned short* lB0a = &Bs[w * 1024 + l * 8];
    unsigned short* lB0b = &Bs[(w + 4) * 1024 + l * 8];
    unsigned short* lB1a = &Bs[w * 1024 + (64 + l) * 8];
    unsigned short* lB1b = &Bs[(w + 4) * 1024 + (64 + l) * 8];

    floatx4 acc[4][4];
#pragma unroll
    for (int mi = 0; mi < 4; ++mi)
#pragma unroll
        for (int ni = 0; ni < 4; ++ni) acc[mi][ni] = (floatx4){0.f, 0.f, 0.f, 0.f};

    for (int k0 = 0; k0 < K; k0 += 64) {
        async_ld16(gA0, lA0a); async_ld16(gA0 + 32, lA0b);
        async_ld16(gA1, lA1a); async_ld16(gA1 + 32, lA1b);
        async_ld16(gB0, lB0a); async_ld16(gB0 + 32, lB0b);
        async_ld16(gB1, lB1a); async_ld16(gB1 + 32, lB1b);
        gA0 += 64; gA1 += 64; gB0 += 64; gB1 += 64;
        __syncthreads();

#pragma unroll
        for (int kk = 0; kk < 2; ++kk) {
            short8 a[4], b[4];
            const int ak = (q + 4 * kk) * 1024;
#pragma unroll
            for (int i = 0; i < 4; ++i)
                a[i] = *(const short8*)&As[ak + (wm + i * 16 + lan) * 8];
#pragma unroll
            for (int i = 0; i < 4; ++i)
                b[i] = *(const short8*)&Bs[ak + (wn + i * 16 + lan) * 8];
#pragma unroll
            for (int mi = 0; mi < 4; ++mi)
#pragma unroll
                for (int ni = 0; ni < 4; ++ni)
                    acc[mi][ni] = __builtin_amdgcn_mfma_f32_16x16x32_bf16(
                        a[mi], b[ni], acc[mi][ni], 0, 0, 0);
        }
        __syncthreads();
    }

    // Epilogue: C/D map col=lane&15, row=(lane>>4)*4+reg
    size_t obase = (size_t)blockIdx.z * oStride;
#pragma unroll
    for (int mi = 0; mi < 4; ++mi) {
#pragma unroll
        for (int r = 0; r < 4; ++r) {
            int mo = m0 + wm + mi * 16 + q * 4 + r;
#pragma unroll
            for (int ni = 0; ni < 4; ++ni) {
                int no = n0 + wn + ni * 16 + lan;
                float v = acc[mi][ni][r];
                if (MODE == 1) {
                    ((unsigned short*)out1)[obase + (size_t)mo * ldo + no] = f2bf(v);
                } else if (MODE == 2) {
                    ((float*)out1)[obase + (size_t)mo * ldo + no] =
                        1.0f / (1.0f + __expf(-v));
                } else if (MODE == 4) {
                    if (no < Nout)
                        atomicAdd(&((float*)out1)[(size_t)mo * ldo + no], v);
                } else if (MODE == 5) {
                    if (no < D_INNER) {
                        ((unsigned short*)out1)[(size_t)mo * D_INNER + no] = f2bf(v);
                    } else {
                        float s = v / (1.0f + __expf(-v));   // silu(z)
                        ((unsigned short*)out2)[(size_t)mo * D_INNER + no - D_INNER] = f2bf(s);
                    }
                } else if (MODE == 6) {
                    float x = v + bias[no];
                    float s = (x > 20.0f) ? x : log1pf(__expf(x));  // softplus
                    ((unsigned short*)out1)[obase + (size_t)mo * ldo + no] = f2bf(s);
                }
            }
        }
    }
}

// ---------------------------------------------------------------------------
// causal depthwise conv1d (k=4) + bias + SiLU: xh bf16 -> xc bf16
// ---------------------------------------------------------------------------
__global__ __launch_bounds__(256)
void conv_silu_kernel(const unsigned short* __restrict__ xh_bf,
                      const float* __restrict__ conv_w,
                      const float* __restrict__ conv_b,
                      unsigned short* __restrict__ xc_bf) {
    int c = blockIdx.x * 256 + threadIdx.x;
    int b = blockIdx.y;
    float4 w = *(const float4*)(conv_w + (size_t)c * 4);
    float bias = conv_b[c];
    const unsigned short* px = xh_bf + (size_t)b * NUM_ACTIONS * D_INNER + c;
    float x[NUM_ACTIONS];
#pragma unroll
    for (int t = 0; t < NUM_ACTIONS; ++t) x[t] = bf2f(px[(size_t)t * D_INNER]);
    unsigned short* po = xc_bf + (size_t)b * NUM_ACTIONS * D_INNER + c;
#pragma unroll
    for (int t = 0; t < NUM_ACTIONS; ++t) {
        float s = bias + x[t] * w.w;
        if (t >= 1) s += x[t - 1] * w.z;
        if (t >= 2) s += x[t - 2] * w.y;
        if (t >= 3) s += x[t - 3] * w.x;
        po[(size_t)t * D_INNER] = f2bf(s * (1.0f / (1.0f + __expf(-s))));  // SiLU
    }
}

// ---------------------------------------------------------------------------
// selective scan (l=8): u/z/delta bf16; B/C from x_dbl via uniform scalar
// loads (SGPR broadcast). ys = y * silu_z in bf16.
// ---------------------------------------------------------------------------
__global__ __launch_bounds__(256)
void scan_kernel(const unsigned short* __restrict__ u_bf,
                 const unsigned short* __restrict__ zs_bf,
                 const unsigned short* __restrict__ delta_bf,
                 const float* __restrict__ x_dbl,
                 const float* __restrict__ A_log, const float* __restrict__ Dp,
                 unsigned short* __restrict__ ys_bf) {
    int b = blockIdx.y;
    int d = blockIdx.x * 256 + threadIdx.x;

    float Av[D_STATE];
    {
        const float4* a4 = (const float4*)(A_log + (size_t)d * D_STATE);
#pragma unroll
        for (int i = 0; i < 4; ++i) {
            float4 v = a4[i];
            Av[4 * i + 0] = -__expf(v.x); Av[4 * i + 1] = -__expf(v.y);
            Av[4 * i + 2] = -__expf(v.z); Av[4 * i + 3] = -__expf(v.w);
        }
    }
    float Dv = Dp[d];
    float h[D_STATE];
#pragma unroll
    for (int n = 0; n < D_STATE; ++n) h[n] = 0.f;

    const float* xd = x_dbl + (size_t)b * NUM_ACTIONS * 96;   // uniform base
#pragma unroll
    for (int t = 0; t < NUM_ACTIONS; ++t) {
        size_t tok = (size_t)(b * NUM_ACTIONS + t);
        float dt = bf2f(delta_bf[tok * D_INNER + d]);
        float uu = bf2f(u_bf[tok * D_INNER + d]);
        float sz = bf2f(zs_bf[tok * D_INNER + d]);
        float du = dt * uu;
        float y = uu * Dv;
#pragma unroll
        for (int n = 0; n < D_STATE; ++n) {
            h[n] = __expf(dt * Av[n]) * h[n] + du * xd[t * 96 + 64 + n];
            y += h[n] * xd[t * 96 + 80 + n];
        }
        ys_bf[tok * D_INNER + d] = f2bf(y * sz);
    }
}

// ---------------------------------------------------------------------------
extern "C" void kernel_launch(void* const* d_in, const int* in_sizes, int n_in,
                              void* d_out, int out_size, void* d_ws, size_t ws_size,
                              hipStream_t stream) {
    const float* enc        = (const float*)d_in[0];
    const int*   actions    = (const int*)d_in[1];
    const float* abe        = (const float*)d_in[2];
    const float* in_proj_w  = (const float*)d_in[4];
    const float* conv_w     = (const float*)d_in[5];
    const float* conv_b     = (const float*)d_in[6];
    const float* x_proj_w   = (const float*)d_in[7];
    const float* dt_proj_w  = (const float*)d_in[8];
    const float* dt_proj_b  = (const float*)d_in[9];
    const float* A_log      = (const float*)d_in[10];
    const float* D_param    = (const float*)d_in[11];
    const float* out_proj_w = (const float*)d_in[12];
    float* out = (float*)d_out;

    // workspace layout
    char* p = (char*)d_ws;
    float* x_dbl = (float*)p;                    p += (size_t)NTOK * 96 * 4;
    unsigned short* xh_bf = (unsigned short*)p;  p += (size_t)NTOK * D_INNER * 2;
    unsigned short* xc_bf = (unsigned short*)p;  p += (size_t)NTOK * D_INNER * 2;
    unsigned short* zs_bf = (unsigned short*)p;  p += (size_t)NTOK * D_INNER * 2;
    unsigned short* delta_bf = (unsigned short*)p; p += (size_t)NTOK * D_INNER * 2;
    unsigned short* ys_bf = (unsigned short*)p;  p += (size_t)NTOK * D_INNER * 2;
    unsigned short* tok_bf = (unsigned short*)p; p += (size_t)NTOK * DIM * 2;
    unsigned short* emb_bf = (unsigned short*)p; p += (size_t)NTOK * DIM * 2;
    unsigned short* inw_bf = (unsigned short*)p; p += (size_t)2 * D_INNER * DIM * 2;
    unsigned short* outw_bf = (unsigned short*)p; p += (size_t)DIM * D_INNER * 2;
    unsigned short* abe_bf = (unsigned short*)p; p += (size_t)NUM_ACTIONS * ACTION_BINS * DIM * 2;
    unsigned short* xpw_bf = (unsigned short*)p; p += (size_t)128 * D_INNER * 2;
    unsigned short* dt_bf = (unsigned short*)p;  p += (size_t)NTOK * DT_RANK * 2;
    unsigned short* dtw_bf = (unsigned short*)p; p += (size_t)D_INNER * DT_RANK * 2;

    // 0) zero x_dbl for split-K atomics
    hipMemsetAsync(x_dbl, 0, (size_t)NTOK * 96 * 4, stream);

    // 1) tokens (bf16) + fused weight conversions
    sos_mean_kernel<<<dim3(1, BATCH), 256, 0, stream>>>(enc, tok_bf);
    gather_tokens_kernel<<<dim3(BATCH, NUM_ACTIONS - 1), 256, 0, stream>>>(actions, abe, tok_bf);
    cvt_all<<<(SEG4 + 255) / 256, 256, 0, stream>>>(
        in_proj_w, out_proj_w, abe, dt_proj_w, x_proj_w,
        inw_bf, outw_bf, abe_bf, dtw_bf, xpw_bf);

    // 2) in_proj (MFMA, XCD-region swizzle 8x8): xh bf16 + silu(z) bf16
    gemm_mfma<5, 8, 8><<<dim3(NTOK / 128, (2 * D_INNER) / 128, 1), 256, 0, stream>>>(
        tok_bf, DIM, 0, inw_bf, DIM, 0, nullptr,
        xh_bf, zs_bf, D_INNER, 0, 2 * D_INNER, DIM, 0);

    // 3) conv + silu -> xc_bf (u)
    conv_silu_kernel<<<dim3(D_INNER / 256, BATCH), 256, 0, stream>>>(xh_bf, conv_w, conv_b, xc_bf);

    // 4) x_proj (MFMA split-K over 8 chunks of 256): x_dbl += xc @ xpw^T
    gemm_mfma<4, 0, 0><<<dim3(NTOK / 128, 1, 8), 256, 0, stream>>>(
        xc_bf, D_INNER, 0, xpw_bf, D_INNER, 0, nullptr,
        x_dbl, nullptr, 96, 0, 128, D_INNER / 8, 96);

    // 5) dt ranks -> bf16; delta = softplus(dt @ dtw^T + b) (MFMA, single k-step)
    cvt_dt<<<256, 256, 0, stream>>>(x_dbl, dt_bf);
    gemm_mfma<6, 0, 0><<<dim3(NTOK / 128, D_INNER / 128, 1), 256, 0, stream>>>(
        dt_bf, DT_RANK, 0, dtw_bf, DT_RANK, 0, dt_proj_b,
        delta_bf, nullptr, D_INNER, 0, D_INNER, DT_RANK, 0);

    // 6) selective scan + y*silu(z) -> ys_bf
    scan_kernel<<<dim3(D_INNER / 256, BATCH), 256, 0, stream>>>(
        xc_bf, zs_bf, delta_bf, x_dbl, A_log, D_param, ys_bf);

    // 7) out_proj (MFMA, XCD-region swizzle 4x8): emb_bf = ys @ out_proj_w^T
    gemm_mfma<1, 4, 8><<<dim3(NTOK / 128, DIM / 128, 1), 256, 0, stream>>>(
        ys_bf, D_INNER, 0, outw_bf, D_INNER, 0, nullptr,
        emb_bf, nullptr, DIM, 0, DIM, D_INNER, 0);

    // 8) logits (MFMA, batched over 8 slots, rolled W, sigmoid)
    gemm_mfma<2, 0, 0><<<dim3(BATCH / 128, ACTION_BINS / 128, NUM_ACTIONS), 256, 0, stream>>>(
        emb_bf, NUM_ACTIONS * DIM, DIM,
        abe_bf, DIM, (long long)ACTION_BINS * DIM, nullptr,
        out, nullptr, NUM_ACTIONS * ACTION_BINS, ACTION_BINS,
        ACTION_BINS, DIM, 0);
}